// Round 7
// baseline (153.161 us; speedup 1.0000x reference)
//
#include <hip/hip_runtime.h>
#include <hip/hip_bf16.h>

typedef __attribute__((ext_vector_type(8))) short short8;
typedef __attribute__((ext_vector_type(4))) float float4v;
typedef __attribute__((ext_vector_type(16))) float float16v;

// Workspace layout (bytes):
//   xTg  bf16 [16 b][32 g][34 h][34 w][8 c]             : 9,469,952
//   Wg   bf16 [9 s][4 pair][4 nq][8 g][64 n][8 c]       : 1,179,648
//   biasout f32 [256]                                   : 1,024
#define XT_BYTES (16*32*34*34*8*2)
#define WG_BYTES (9*4*4*8*64*8*2)

// ---------------------------------------------------------------------------
// k_prep: fused producer. (unchanged from R12)
// ---------------------------------------------------------------------------
__global__ __launch_bounds__(256) void k_prep(const float* __restrict__ x,
                                              const float* __restrict__ tw1,
                                              const float* __restrict__ tw2,
                                              const float* __restrict__ bias,
                                              __hip_bfloat16* __restrict__ xTg,
                                              __hip_bfloat16* __restrict__ Wg,
                                              float* __restrict__ biasout) {
  __shared__ __align__(16) char smem[256 * 33 * 4];   // 33792 B, both phases fit
  int blk = blockIdx.x;
  int tid = threadIdx.x;

  if (blk < 512) {   // ---------------- transpose ----------------
    float* tile = (float*)smem;
    char* xTB = (char*)xTg;
    int h = blk & 31, b = blk >> 5;
    {
      int w4 = (tid & 7) * 4, c0 = tid >> 3;
#pragma unroll
      for (int j = 0; j < 8; ++j) {
        int ci = c0 + 32 * j;
        float4 v = *(const float4*)&x[((b * 256 + ci) * 32 + h) * 32 + w4];
        *(float4*)&tile[ci * 33 + w4] = v;
      }
    }
    __syncthreads();
    {
      int g0 = tid >> 5, w = tid & 31;
#pragma unroll
      for (int gi = 0; gi < 4; ++gi) {
        int g = gi * 8 + g0;
        union { short8 s; __hip_bfloat16 hv[8]; } pk;
#pragma unroll
        for (int cc = 0; cc < 8; ++cc)
          pk.hv[cc] = __float2bfloat16(tile[(g * 8 + cc) * 33 + w]);
        *(short8*)(xTB + ((((b * 32 + g) * 34 + h + 1) * 34) + (w + 1)) * 16) = pk.s;
      }
    }
    if (h < 2) {  // h==0 -> row 0 + col 0 ; h==1 -> row 33 + col 33 (all g)
      uint4 z4 = {0u, 0u, 0u, 0u};
      int edge = h * 33;
      for (int i = tid; i < 32 * 34; i += 256) {
        int g = i / 34, w = i - g * 34;
        *(uint4*)(xTB + ((((b * 32 + g) * 34 + edge) * 34) + w) * 16) = z4;
      }
      for (int i = tid; i < 32 * 32; i += 256) {
        int g = i >> 5, hh = 1 + (i & 31);
        *(uint4*)(xTB + ((((b * 32 + g) * 34 + hh) * 34) + edge) * 16) = z4;
      }
    }
    return;
  }

  // ---------------- build_w ----------------
  int wblk = blk - 512;
  if (wblk == 144) {
    if (tid < 256) {
      float a = 0.f;
#pragma unroll
      for (int s = 0; s < 9; ++s) a += bias[s * 256 + tid];
      biasout[tid] = a * (1.f / 9.f);
    }
    return;
  }
  float* mat = (float*)smem;              // 256*17*4 = 17408 B
  float* tws = (float*)(smem + 17408);    // 2*255*4*4 = 8160 B
  int sidx = wblk >> 4;
  int colbase = (wblk & 15) * 16;

  for (int i = tid; i < 255 * 4; i += 256) {
    tws[i]           = tw1[sidx * 255 * 4 + i];
    tws[255 * 4 + i] = tw2[sidx * 255 * 4 + i];
  }
  {
    int r = tid;
#pragma unroll
    for (int c = 0; c < 16; ++c) mat[r * 17 + c] = (r == colbase + c) ? 1.f : 0.f;
  }

  int c  = tid & 15;
  int pg = tid >> 4;
  for (int ph = 0; ph < 2; ++ph) {
    for (int si = 0; si < 8; ++si) {
      int lg = ph ? si : (7 - si);
      int st = 1 << lg;
      __syncthreads();
      float x0[8], x1[8], t0[8], t1[8], t2[8], t3[8];
#pragma unroll
      for (int i = 0; i < 8; ++i) {
        int qp = pg * 8 + i;
        int li = qp & (st - 1);
        int gi = qp >> lg;
        int p0 = (gi << (lg + 1)) | li;
        int p1 = p0 + st;
        float4 tv = *(const float4*)&tws[(ph * 255 + st - 1 + li) * 4];
        t0[i] = tv.x; t1[i] = tv.y; t2[i] = tv.z; t3[i] = tv.w;
        x0[i] = mat[p0 * 17 + c];
        x1[i] = mat[p1 * 17 + c];
      }
#pragma unroll
      for (int i = 0; i < 8; ++i) {
        int qp = pg * 8 + i;
        int li = qp & (st - 1);
        int gi = qp >> lg;
        int p0 = (gi << (lg + 1)) | li;
        int p1 = p0 + st;
        mat[p0 * 17 + c] = t0[i] * x0[i] + t1[i] * x1[i];
        mat[p1 * 17 + c] = t2[i] * x0[i] + t3[i] * x1[i];
      }
    }
  }
  __syncthreads();

  for (int idx = tid; idx < 256 * 16; idx += 256) {
    int r = idx >> 4, cc = idx & 15;
    int cg = colbase + cc;
    int pr = cg >> 6, g = (cg >> 3) & 7, c8 = cg & 7;
    int nq = r >> 6, nl = r & 63;
    int o = ((((sidx * 4 + pr) * 4 + nq) * 8 + g) * 64 + nl) * 8 + c8;
    Wg[o] = __float2bfloat16(mat[r * 17 + cc] * (1.f / 9.f));
  }
}

// ---------------------------------------------------------------------------
// k_gemm R19 COUNTER-VISIBILITY PROBE = R18 (XCD swizzle, current best) with
// the K-loop repeated x4 (all reps accumulate -> DCE-proof; epilogue scales
// by 0.25f -- exact-fp scale, ulp-level absmax change only). Purpose: the
// dispatch grows to ~90 µs > the 45-µs harness fills, so k_gemm finally
// enters the rocprof top-5 with real MfmaUtil / VALUBusy / FETCH_SIZE /
// Occupancy / VGPR columns. Also: dur delta vs 108.8 = 3 x T_loop, splitting
// the 28 µs gemm budget into K-loop vs epilogue+overhead. Three consecutive
// gemm theories (R13 latency-pipe null, R16 LDS-B regression, R18 XCD null)
// died without counters -- this round buys them.
// ---------------------------------------------------------------------------
__global__ __launch_bounds__(256, 2) void k_gemm(const __hip_bfloat16* __restrict__ xTg,
                                                 const __hip_bfloat16* __restrict__ Wg,
                                                 const float* __restrict__ biasout,
                                                 float* __restrict__ out) {
  __shared__ __align__(64) char lds[32768];
  const char* WgB = (const char*)Wg;
  const char* xTB = (const char*)xTg;

  // XCD swizzle (R18): xcd = blk&7 owns b in {2*xcd, 2*xcd+1}.
  int blk  = blockIdx.x;
  int rest = blk >> 3;
  int b    = 2 * (blk & 7) + (rest >> 5);
  int i32  = rest & 31;
  int nq   = i32 & 3;
  int pt   = i32 >> 2;
  int h0   = pt * 4;              // output rows h0..h0+3

  int tid  = threadIdx.x;
  int lane = tid & 63;
  int wk   = tid >> 6;            // wave = k-quarter 0..3
  int half = lane >> 5;
  int l31  = lane & 31;

  float16v acc[2][4];             // [mt][p2]
#pragma unroll
  for (int mt = 0; mt < 2; ++mt)
#pragma unroll
    for (int p2 = 0; p2 < 4; ++p2)
#pragma unroll
      for (int e = 0; e < 16; ++e) acc[mt][p2][e] = 0.f;

  // A: within a slab, octet (2wk+half), row mt*32+l31 -> 16 B/lane contiguous.
  int aoff = ((2 * wk + half) * 64 + l31) * 16;
  // B: octet (2wk+half) of chan-pair p (global octet +8p), padded row h0, col l31.
  int bbase = ((((b * 32 + 2 * wk + half) * 34 + h0) * 34) + l31) * 16;

#pragma unroll 1
  for (int rep = 0; rep < 4; ++rep) {   // x4 K-loop repeat (probe)
#pragma unroll 2
    for (int p = 0; p < 4; ++p) {
      const char* Bp = xTB + bbase + p * (8 * 34 * 34) * 16;
      const char* Ap = WgB + (p * 4 + nq) * 8192;
#pragma unroll
      for (int si = 0; si < 3; ++si) {
#pragma unroll
        for (int sj = 0; sj < 3; ++sj) {
          const char* Aslab = Ap + (si * 3 + sj) * (16 * 8192);
          short8 a0 = *(const short8*)(Aslab + aoff);
          short8 a1 = *(const short8*)(Aslab + aoff + 32 * 16);
          const char* Bq = Bp + (si * 34 + sj) * 16;
          short8 b0 = *(const short8*)(Bq);
          short8 b1 = *(const short8*)(Bq + 34 * 16);
          short8 b2 = *(const short8*)(Bq + 68 * 16);
          short8 b3 = *(const short8*)(Bq + 102 * 16);
          acc[0][0] = __builtin_amdgcn_mfma_f32_32x32x16_bf16(a0, b0, acc[0][0], 0, 0, 0);
          acc[0][1] = __builtin_amdgcn_mfma_f32_32x32x16_bf16(a0, b1, acc[0][1], 0, 0, 0);
          acc[0][2] = __builtin_amdgcn_mfma_f32_32x32x16_bf16(a0, b2, acc[0][2], 0, 0, 0);
          acc[0][3] = __builtin_amdgcn_mfma_f32_32x32x16_bf16(a0, b3, acc[0][3], 0, 0, 0);
          acc[1][0] = __builtin_amdgcn_mfma_f32_32x32x16_bf16(a1, b0, acc[1][0], 0, 0, 0);
          acc[1][1] = __builtin_amdgcn_mfma_f32_32x32x16_bf16(a1, b1, acc[1][1], 0, 0, 0);
          acc[1][2] = __builtin_amdgcn_mfma_f32_32x32x16_bf16(a1, b2, acc[1][2], 0, 0, 0);
          acc[1][3] = __builtin_amdgcn_mfma_f32_32x32x16_bf16(a1, b3, acc[1][3], 0, 0, 0);
        }
      }
    }
  }

  // k-quarter reduction. Conflict-free: slot*4096 + lane*16, 4 chunks @ +1024.
  auto st16 = [&](int slot, const float16v& v) {
    char* base = lds + slot * 4096 + lane * 16;
    *(float4v*)(base)        = (float4v){v[0],  v[1],  v[2],  v[3]};
    *(float4v*)(base + 1024) = (float4v){v[4],  v[5],  v[6],  v[7]};
    *(float4v*)(base + 2048) = (float4v){v[8],  v[9],  v[10], v[11]};
    *(float4v*)(base + 3072) = (float4v){v[12], v[13], v[14], v[15]};
  };
  auto ld16add = [&](int slot, float16v& v) {
    const char* base = lds + slot * 4096 + lane * 16;
    float4v t0 = *(const float4v*)(base);
    float4v t1 = *(const float4v*)(base + 1024);
    float4v t2 = *(const float4v*)(base + 2048);
    float4v t3 = *(const float4v*)(base + 3072);
    v[0] += t0[0]; v[1] += t0[1]; v[2]  += t0[2]; v[3]  += t0[3];
    v[4] += t1[0]; v[5] += t1[1]; v[6]  += t1[2]; v[7]  += t1[3];
    v[8] += t2[0]; v[9] += t2[1]; v[10] += t2[2]; v[11] += t2[3];
    v[12] += t3[0]; v[13] += t3[1]; v[14] += t3[2]; v[15] += t3[3];
  };

  __syncthreads();
  if (wk >= 2) {
#pragma unroll
    for (int p2 = 0; p2 < 4; ++p2) st16((wk - 2) * 4 + p2, acc[0][p2]);
  }
  __syncthreads();
  if (wk < 2) {
#pragma unroll
    for (int p2 = 0; p2 < 4; ++p2) ld16add(wk * 4 + p2, acc[0][p2]);
  }
  __syncthreads();
  if (wk >= 2) {
#pragma unroll
    for (int p2 = 0; p2 < 4; ++p2) st16((wk - 2) * 4 + p2, acc[1][p2]);
  }
  __syncthreads();
  if (wk < 2) {
#pragma unroll
    for (int p2 = 0; p2 < 4; ++p2) ld16add(wk * 4 + p2, acc[1][p2]);
  }
  __syncthreads();
  if (wk == 1) {
#pragma unroll
    for (int p2 = 0; p2 < 4; ++p2) { st16(p2, acc[0][p2]); st16(4 + p2, acc[1][p2]); }
  }
  __syncthreads();
  if (wk == 0) {
#pragma unroll
    for (int p2 = 0; p2 < 4; ++p2) { ld16add(p2, acc[0][p2]); ld16add(4 + p2, acc[1][p2]); }
    // Store 64n x 128pix. D layout: col=l31, row=(reg&3)+8*(reg>>2)+4*half.
    // x0.25f undoes the x4 K-loop repeat (exact fp scale).
#pragma unroll
    for (int mt = 0; mt < 2; ++mt) {
#pragma unroll
      for (int reg = 0; reg < 16; ++reg) {
        int n = nq * 64 + mt * 32 + (reg & 3) + 8 * (reg >> 2) + 4 * half;
        float bv = biasout[n];
#pragma unroll
        for (int p2 = 0; p2 < 4; ++p2)
          out[((b * 256 + n) * 32 + h0 + p2) * 32 + l31] = acc[mt][p2][reg] * 0.25f + bv;
      }
    }
  }
}

// ---------------------------------------------------------------------------
extern "C" void kernel_launch(void* const* d_in, const int* in_sizes, int n_in,
                              void* d_out, int out_size, void* d_ws, size_t ws_size,
                              hipStream_t stream) {
  const float* x    = (const float*)d_in[0];
  const float* tw1  = (const float*)d_in[1];
  const float* tw2  = (const float*)d_in[2];
  const float* bias = (const float*)d_in[3];
  float* out = (float*)d_out;

  char* ws = (char*)d_ws;
  __hip_bfloat16* xTg = (__hip_bfloat16*)ws;
  __hip_bfloat16* Wg  = (__hip_bfloat16*)(ws + XT_BYTES);
  float* biasout      = (float*)(ws + XT_BYTES + WG_BYTES);

  k_prep<<<657, 256, 0, stream>>>(x, tw1, tw2, bias, xTg, Wg, biasout);
  k_gemm<<<512, 256, 0, stream>>>(xTg, Wg, biasout, out);
}

// Round 9
// 108.357 us; speedup vs baseline: 1.4135x; 1.4135x over previous
//
#include <hip/hip_runtime.h>
#include <hip/hip_bf16.h>

typedef __attribute__((ext_vector_type(8))) short short8;
typedef __attribute__((ext_vector_type(4))) float float4v;
typedef __attribute__((ext_vector_type(16))) float float16v;

// Workspace layout (bytes):
//   xTg  bf16 [16 b][32 g][34 h][34 w][8 c]             : 9,469,952
//   Wg   bf16 [9 s][4 pair][4 nq][8 g][64 n][8 c]       : 1,179,648
//   biasout f32 [256]                                   : 1,024
#define XT_BYTES (16*32*34*34*8*2)
#define WG_BYTES (9*4*4*8*64*8*2)

// ---------------------------------------------------------------------------
// k_prep: fused producer. (unchanged from R12)
// ---------------------------------------------------------------------------
__global__ __launch_bounds__(256) void k_prep(const float* __restrict__ x,
                                              const float* __restrict__ tw1,
                                              const float* __restrict__ tw2,
                                              const float* __restrict__ bias,
                                              __hip_bfloat16* __restrict__ xTg,
                                              __hip_bfloat16* __restrict__ Wg,
                                              float* __restrict__ biasout) {
  __shared__ __align__(16) char smem[256 * 33 * 4];   // 33792 B, both phases fit
  int blk = blockIdx.x;
  int tid = threadIdx.x;

  if (blk < 512) {   // ---------------- transpose ----------------
    float* tile = (float*)smem;
    char* xTB = (char*)xTg;
    int h = blk & 31, b = blk >> 5;
    {
      int w4 = (tid & 7) * 4, c0 = tid >> 3;
#pragma unroll
      for (int j = 0; j < 8; ++j) {
        int ci = c0 + 32 * j;
        float4 v = *(const float4*)&x[((b * 256 + ci) * 32 + h) * 32 + w4];
        *(float4*)&tile[ci * 33 + w4] = v;
      }
    }
    __syncthreads();
    {
      int g0 = tid >> 5, w = tid & 31;
#pragma unroll
      for (int gi = 0; gi < 4; ++gi) {
        int g = gi * 8 + g0;
        union { short8 s; __hip_bfloat16 hv[8]; } pk;
#pragma unroll
        for (int cc = 0; cc < 8; ++cc)
          pk.hv[cc] = __float2bfloat16(tile[(g * 8 + cc) * 33 + w]);
        *(short8*)(xTB + ((((b * 32 + g) * 34 + h + 1) * 34) + (w + 1)) * 16) = pk.s;
      }
    }
    if (h < 2) {  // h==0 -> row 0 + col 0 ; h==1 -> row 33 + col 33 (all g)
      uint4 z4 = {0u, 0u, 0u, 0u};
      int edge = h * 33;
      for (int i = tid; i < 32 * 34; i += 256) {
        int g = i / 34, w = i - g * 34;
        *(uint4*)(xTB + ((((b * 32 + g) * 34 + edge) * 34) + w) * 16) = z4;
      }
      for (int i = tid; i < 32 * 32; i += 256) {
        int g = i >> 5, hh = 1 + (i & 31);
        *(uint4*)(xTB + ((((b * 32 + g) * 34 + hh) * 34) + edge) * 16) = z4;
      }
    }
    return;
  }

  // ---------------- build_w ----------------
  int wblk = blk - 512;
  if (wblk == 144) {
    if (tid < 256) {
      float a = 0.f;
#pragma unroll
      for (int s = 0; s < 9; ++s) a += bias[s * 256 + tid];
      biasout[tid] = a * (1.f / 9.f);
    }
    return;
  }
  float* mat = (float*)smem;              // 256*17*4 = 17408 B
  float* tws = (float*)(smem + 17408);    // 2*255*4*4 = 8160 B
  int sidx = wblk >> 4;
  int colbase = (wblk & 15) * 16;

  for (int i = tid; i < 255 * 4; i += 256) {
    tws[i]           = tw1[sidx * 255 * 4 + i];
    tws[255 * 4 + i] = tw2[sidx * 255 * 4 + i];
  }
  {
    int r = tid;
#pragma unroll
    for (int c = 0; c < 16; ++c) mat[r * 17 + c] = (r == colbase + c) ? 1.f : 0.f;
  }

  int c  = tid & 15;
  int pg = tid >> 4;
  for (int ph = 0; ph < 2; ++ph) {
    for (int si = 0; si < 8; ++si) {
      int lg = ph ? si : (7 - si);
      int st = 1 << lg;
      __syncthreads();
      float x0[8], x1[8], t0[8], t1[8], t2[8], t3[8];
#pragma unroll
      for (int i = 0; i < 8; ++i) {
        int qp = pg * 8 + i;
        int li = qp & (st - 1);
        int gi = qp >> lg;
        int p0 = (gi << (lg + 1)) | li;
        int p1 = p0 + st;
        float4 tv = *(const float4*)&tws[(ph * 255 + st - 1 + li) * 4];
        t0[i] = tv.x; t1[i] = tv.y; t2[i] = tv.z; t3[i] = tv.w;
        x0[i] = mat[p0 * 17 + c];
        x1[i] = mat[p1 * 17 + c];
      }
#pragma unroll
      for (int i = 0; i < 8; ++i) {
        int qp = pg * 8 + i;
        int li = qp & (st - 1);
        int gi = qp >> lg;
        int p0 = (gi << (lg + 1)) | li;
        int p1 = p0 + st;
        mat[p0 * 17 + c] = t0[i] * x0[i] + t1[i] * x1[i];
        mat[p1 * 17 + c] = t2[i] * x0[i] + t3[i] * x1[i];
      }
    }
  }
  __syncthreads();

  for (int idx = tid; idx < 256 * 16; idx += 256) {
    int r = idx >> 4, cc = idx & 15;
    int cg = colbase + cc;
    int pr = cg >> 6, g = (cg >> 3) & 7, c8 = cg & 7;
    int nq = r >> 6, nl = r & 63;
    int o = ((((sidx * 4 + pr) * 4 + nq) * 8 + g) * 64 + nl) * 8 + c8;
    Wg[o] = __float2bfloat16(mat[r * 17 + cc] * (1.f / 9.f));
  }
}

// ---------------------------------------------------------------------------
// k_gemm R21 (= R20 resubmit after container infra failure): occupancy
// 2 -> 4 waves/SIMD.
// R19 counters (x4 probe): FETCH 9.3 MB (compulsory only), VALUBusy 8%,
// bank conflicts 0, real per-SIMD MFMA util ~13% -> the loop (15.9 µs of 28)
// is ~87% exposed cache-hit latency at only 2 waves/SIMD (acc[2][4]=128 regs
// capped occupancy). Fix: halve the pixel tile -- acc[2][2] (64 regs), grid
// 512 -> 1024 (h0 = pt*2), __launch_bounds__(256,4) -> 4 waves/SIMD,
// 4 blocks/CU, LDS 16 KB. Per-acc summation order unchanged (p outer,
// si/sj inner) -> bit-identical results. Epilogue tree: half the slots,
// half the stores per block, 2x more blocks. XCD swizzle (R18) retained.
// ---------------------------------------------------------------------------
__global__ __launch_bounds__(256, 4) void k_gemm(const __hip_bfloat16* __restrict__ xTg,
                                                 const __hip_bfloat16* __restrict__ Wg,
                                                 const float* __restrict__ biasout,
                                                 float* __restrict__ out) {
  __shared__ __align__(64) char lds[16384];
  const char* WgB = (const char*)Wg;
  const char* xTB = (const char*)xTg;

  // XCD swizzle: xcd = blk&7 owns b in {2*xcd, 2*xcd+1}. Grid 1024.
  int blk  = blockIdx.x;
  int rest = blk >> 3;              // 0..127
  int b    = 2 * (blk & 7) + (rest >> 6);
  int r2   = rest & 63;
  int nq   = r2 & 3;
  int pt   = r2 >> 2;               // 0..15
  int h0   = pt * 2;                // output rows h0, h0+1

  int tid  = threadIdx.x;
  int lane = tid & 63;
  int wk   = tid >> 6;              // wave = k-quarter 0..3
  int half = lane >> 5;
  int l31  = lane & 31;

  float16v acc[2][2];               // [mt][p2] -- 64 regs
#pragma unroll
  for (int mt = 0; mt < 2; ++mt)
#pragma unroll
    for (int p2 = 0; p2 < 2; ++p2)
#pragma unroll
      for (int e = 0; e < 16; ++e) acc[mt][p2][e] = 0.f;

  // A: within a slab, octet (2wk+half), rows mt*32+l31 (+512 B for mt=1).
  int aoff = ((2 * wk + half) * 64 + l31) * 16;
  // B: octet (2wk+half) of chan-pair p, padded row h0, col l31.
  int bbase = ((((b * 32 + 2 * wk + half) * 34 + h0) * 34) + l31) * 16;

#pragma unroll 2
  for (int p = 0; p < 4; ++p) {
    const char* Bp = xTB + bbase + p * (8 * 34 * 34) * 16;
    const char* Ap = WgB + (p * 4 + nq) * 8192;
#pragma unroll
    for (int si = 0; si < 3; ++si) {
#pragma unroll
      for (int sj = 0; sj < 3; ++sj) {
        const char* Aslab = Ap + (si * 3 + sj) * (16 * 8192);
        short8 a0 = *(const short8*)(Aslab + aoff);
        short8 a1 = *(const short8*)(Aslab + aoff + 32 * 16);
        const char* Bq = Bp + (si * 34 + sj) * 16;
        short8 b0 = *(const short8*)(Bq);
        short8 b1 = *(const short8*)(Bq + 34 * 16);
        acc[0][0] = __builtin_amdgcn_mfma_f32_32x32x16_bf16(a0, b0, acc[0][0], 0, 0, 0);
        acc[0][1] = __builtin_amdgcn_mfma_f32_32x32x16_bf16(a0, b1, acc[0][1], 0, 0, 0);
        acc[1][0] = __builtin_amdgcn_mfma_f32_32x32x16_bf16(a1, b0, acc[1][0], 0, 0, 0);
        acc[1][1] = __builtin_amdgcn_mfma_f32_32x32x16_bf16(a1, b1, acc[1][1], 0, 0, 0);
      }
    }
  }

  // k-quarter reduction. Conflict-free: slot*4096 + lane*16, 4 chunks @ +1024.
  auto st16 = [&](int slot, const float16v& v) {
    char* base = lds + slot * 4096 + lane * 16;
    *(float4v*)(base)        = (float4v){v[0],  v[1],  v[2],  v[3]};
    *(float4v*)(base + 1024) = (float4v){v[4],  v[5],  v[6],  v[7]};
    *(float4v*)(base + 2048) = (float4v){v[8],  v[9],  v[10], v[11]};
    *(float4v*)(base + 3072) = (float4v){v[12], v[13], v[14], v[15]};
  };
  auto ld16add = [&](int slot, float16v& v) {
    const char* base = lds + slot * 4096 + lane * 16;
    float4v t0 = *(const float4v*)(base);
    float4v t1 = *(const float4v*)(base + 1024);
    float4v t2 = *(const float4v*)(base + 2048);
    float4v t3 = *(const float4v*)(base + 3072);
    v[0] += t0[0]; v[1] += t0[1]; v[2]  += t0[2]; v[3]  += t0[3];
    v[4] += t1[0]; v[5] += t1[1]; v[6]  += t1[2]; v[7]  += t1[3];
    v[8] += t2[0]; v[9] += t2[1]; v[10] += t2[2]; v[11] += t2[3];
    v[12] += t3[0]; v[13] += t3[1]; v[14] += t3[2]; v[15] += t3[3];
  };

  __syncthreads();
  if (wk >= 2) {           // slots (wk-2)*2 + p2  -> 0..3
#pragma unroll
    for (int p2 = 0; p2 < 2; ++p2) st16((wk - 2) * 2 + p2, acc[0][p2]);
  }
  __syncthreads();
  if (wk < 2) {
#pragma unroll
    for (int p2 = 0; p2 < 2; ++p2) ld16add(wk * 2 + p2, acc[0][p2]);
  }
  __syncthreads();
  if (wk >= 2) {
#pragma unroll
    for (int p2 = 0; p2 < 2; ++p2) st16((wk - 2) * 2 + p2, acc[1][p2]);
  }
  __syncthreads();
  if (wk < 2) {
#pragma unroll
    for (int p2 = 0; p2 < 2; ++p2) ld16add(wk * 2 + p2, acc[1][p2]);
  }
  __syncthreads();
  if (wk == 1) {           // slots p2 (acc[0]) and 2+p2 (acc[1])
#pragma unroll
    for (int p2 = 0; p2 < 2; ++p2) { st16(p2, acc[0][p2]); st16(2 + p2, acc[1][p2]); }
  }
  __syncthreads();
  if (wk == 0) {
#pragma unroll
    for (int p2 = 0; p2 < 2; ++p2) { ld16add(p2, acc[0][p2]); ld16add(2 + p2, acc[1][p2]); }
    // Store 64n x 64pix. D layout: col=l31, row=(reg&3)+8*(reg>>2)+4*half.
#pragma unroll
    for (int mt = 0; mt < 2; ++mt) {
#pragma unroll
      for (int reg = 0; reg < 16; ++reg) {
        int n = nq * 64 + mt * 32 + (reg & 3) + 8 * (reg >> 2) + 4 * half;
        float bv = biasout[n];
#pragma unroll
        for (int p2 = 0; p2 < 2; ++p2)
          out[((b * 256 + n) * 32 + h0 + p2) * 32 + l31] = acc[mt][p2][reg] + bv;
      }
    }
  }
}

// ---------------------------------------------------------------------------
extern "C" void kernel_launch(void* const* d_in, const int* in_sizes, int n_in,
                              void* d_out, int out_size, void* d_ws, size_t ws_size,
                              hipStream_t stream) {
  const float* x    = (const float*)d_in[0];
  const float* tw1  = (const float*)d_in[1];
  const float* tw2  = (const float*)d_in[2];
  const float* bias = (const float*)d_in[3];
  float* out = (float*)d_out;

  char* ws = (char*)d_ws;
  __hip_bfloat16* xTg = (__hip_bfloat16*)ws;
  __hip_bfloat16* Wg  = (__hip_bfloat16*)(ws + XT_BYTES);
  float* biasout      = (float*)(ws + XT_BYTES + WG_BYTES);

  k_prep<<<657, 256, 0, stream>>>(x, tw1, tw2, bias, xTg, Wg, biasout);
  k_gemm<<<1024, 256, 0, stream>>>(xTg, Wg, biasout, out);
}